// Round 8
// baseline (340.870 us; speedup 1.0000x reference)
//
#include <hip/hip_runtime.h>

#define NN 100000
#define NE 1600000
#define NB 782            // buckets of 128 dst nodes
#define NBPAD 1024        // padded bucket count (1 per thread in 1024-thread binfill)
#define CAPB 3072         // staging/grouped capacity per bucket (mean 2046, 22 sigma)
#define EPB 8192          // edges per binning block (196 blocks, benign atomic count)
#define BFT 1024          // binfill threads (16 waves/CU -> latency cover)
#define NPB 1563          // pull blocks per chunk: ceil(NN/64)
#define NROWPAD 100096    // 782 * 128, dgemm row padding
#define DPAD 136          // T-tile row stride (ushort)
#define OPAD 72           // O-tile row stride (ushort)

typedef __attribute__((ext_vector_type(8))) short short8;
typedef __attribute__((ext_vector_type(4))) float f32x4;
typedef __attribute__((ext_vector_type(2))) unsigned u32x2;

// ---------------- helpers ----------------
__device__ __forceinline__ unsigned short bf16rn(float f) {
    unsigned u = __float_as_uint(f);
    return (unsigned short)((u + 0x7FFFu + ((u >> 16) & 1u)) >> 16);
}
__device__ __forceinline__ uint2 packbf4(float4 v) {
    uint2 u;
    u.x = (unsigned)bf16rn(v.x) | ((unsigned)bf16rn(v.y) << 16);
    u.y = (unsigned)bf16rn(v.z) | ((unsigned)bf16rn(v.w) << 16);
    return u;
}
// accumulate 4 bf16 features (one uint2) scaled by q
__device__ __forceinline__ void acc4(float4& a, uint2 v, float q) {
    a.x = fmaf(__uint_as_float(v.x << 16), q, a.x);
    a.y = fmaf(__uint_as_float(v.x & 0xFFFF0000u), q, a.y);
    a.z = fmaf(__uint_as_float(v.y << 16), q, a.z);
    a.w = fmaf(__uint_as_float(v.y & 0xFFFF0000u), q, a.w);
}
// decode 15-bit packed dinv[src]: exp in [112,127], 11-bit mantissa
__device__ __forceinline__ float decq(unsigned e) {
    return __uint_as_float(0x38000000u | ((e & 0x7FFFu) << 12));
}

// ---------------- dtype detector ----------------
__global__ void detect_i64_k(const unsigned* __restrict__ ei, int* __restrict__ flag) {
    unsigned w = ei[2 * threadIdx.x + 1];
    unsigned long long b = __ballot(w == 0u);
    if (threadIdx.x == 0) *flag = (b == 0xFFFFFFFFFFFFFFFFull) ? 1 : 0;
}
__device__ __forceinline__ int load_node(const void* ei, int i64, long long idx) {
    return i64 ? (int)((const long long*)ei)[idx] : ((const int*)ei)[idx];
}

// ---------------- fp32 -> bf16 cast, CHUNKED layout: xc[ch][node][16 feats] ----------------
__global__ void cast_xc_k(const float* __restrict__ in, ushort* __restrict__ xc) {
    long long i = (long long)blockIdx.x * 256 + threadIdx.x;   // uint2 index, NN*32 total
    if (i >= (long long)NN * 32) return;
    int node = (int)(i >> 5);
    int fq = (int)(i & 31);          // 4-feature group within row
    int ch = fq >> 2, ln = fq & 3;   // chunk of 16 feats, uint2 within chunk row
    ((uint2*)xc)[(long long)ch * (NN * 4) + (long long)node * 4 + ln] =
        packbf4(((const float4*)in)[i]);
}

// ---------------- weights -> bf16 col-major ----------------
__global__ void prep_wt_k(const float* __restrict__ W1, const float* __restrict__ W2,
                          ushort* __restrict__ W1t, ushort* __restrict__ W2t) {
    int i = blockIdx.x * 256 + threadIdx.x;
    if (i < 128 * 128) {
        int k = i >> 7, n = i & 127;
        W1t[n * 128 + k] = bf16rn(W1[k * 128 + n]);
    }
    if (i < 128 * 64) {
        int k = i >> 6, n = i & 63;
        W2t[n * 128 + k] = bf16rn(W2[k * 64 + n]);
    }
}

// ---------------- LDS-staged binning, 1024 threads (proven round 6) ----------------
__global__ __launch_bounds__(1024) void binfill_k(const void* __restrict__ ei,
                                                  const int* __restrict__ flag,
                                                  int* __restrict__ cur,
                                                  unsigned* __restrict__ bstage) {
    __shared__ unsigned binned[EPB];      // 32 KB
    __shared__ int lcnt[NBPAD];
    __shared__ int lpos[NBPAD];
    __shared__ int gbase[NBPAD];
    __shared__ int tsum[NBPAD];
    int tid = threadIdx.x;
    long long e0 = (long long)blockIdx.x * EPB;
    int i64 = *flag;

    lcnt[tid] = 0;
    __syncthreads();

    for (int i = tid; i < EPB; i += BFT) {
        long long e = e0 + i;
        if (e < NE) {
            int d = load_node(ei, i64, (long long)NE + e);
            atomicAdd(&lcnt[d >> 7], 1);
        }
    }
    __syncthreads();

    int c = lcnt[tid];
    tsum[tid] = c;
    __syncthreads();
    for (int off = 1; off < NBPAD; off <<= 1) {
        int v = (tid >= off) ? tsum[tid - off] : 0;
        __syncthreads();
        tsum[tid] += v;
        __syncthreads();
    }
    int excl = tsum[tid] - c;
    lcnt[tid] = excl;
    lpos[tid] = excl;
    if (tid < NB) gbase[tid] = c ? atomicAdd(&cur[tid], c) : 0;
    __syncthreads();

    for (int i = tid; i < EPB; i += BFT) {
        long long e = e0 + i;
        if (e < NE) {
            int sv = load_node(ei, i64, e);
            int d  = load_node(ei, i64, (long long)NE + e);
            int b  = d >> 7;
            int p  = atomicAdd(&lpos[b], 1);
            binned[p] = ((unsigned)(d & 127) << 17) | (unsigned)sv;
        }
    }
    __syncthreads();

    if (tid < NB) {
        int start = lcnt[tid], endp = lpos[tid];
        int gb = gbase[tid];
        unsigned* dst = bstage + (long long)tid * CAPB;
        for (int k = start; k < endp; k++) {
            int go = gb + (k - start);
            if (go < CAPB) dst[go] = binned[k];
        }
    }
}

// ---------------- per-bucket LDS regroup -> dense CSR (plain src ints) + deg ----------------
__global__ __launch_bounds__(256) void regroup_k(const int* __restrict__ cur,
                                                 const unsigned* __restrict__ bstage,
                                                 int* __restrict__ cnt,
                                                 int* __restrict__ rowstart,
                                                 unsigned* __restrict__ grouped,
                                                 float* __restrict__ dinv) {
    __shared__ unsigned stash[CAPB];
    __shared__ unsigned srt[CAPB];
    __shared__ int lcnt[128], lofs[128], lpos[128], sc[128];
    int tid = threadIdx.x;
    int b = blockIdx.x;

    int total = cur[b];
    if (total > CAPB) total = CAPB;
    const unsigned* seg = bstage + (long long)b * CAPB;
    for (int i = tid; i < total; i += 256) stash[i] = seg[i];
    __syncthreads();

    if (tid < 128) { lcnt[tid] = 0; lpos[tid] = 0; }
    __syncthreads();
    for (int i = tid; i < total; i += 256)
        atomicAdd(&lcnt[stash[i] >> 17], 1);
    __syncthreads();

    if (tid < 128) sc[tid] = lcnt[tid];
    __syncthreads();
    for (int off = 1; off < 128; off <<= 1) {
        int v = 0;
        if (tid < 128 && tid >= off) v = sc[tid - off];
        __syncthreads();
        if (tid < 128) sc[tid] += v;
        __syncthreads();
    }
    if (tid < 128) {
        lofs[tid] = sc[tid] - lcnt[tid];
        int node = b * 128 + tid;
        if (node < NN) {
            cnt[node] = lcnt[tid];
            rowstart[node] = b * CAPB + lofs[tid];
            dinv[node] = rsqrtf((float)(lcnt[tid] + 1));   // +1: self-loop
        }
    }
    __syncthreads();

    for (int i = tid; i < total; i += 256) {
        unsigned e = stash[i];
        int nl = e >> 17;
        int p = atomicAdd(&lpos[nl], 1);
        srt[lofs[nl] + p] = e;
    }
    __syncthreads();

    unsigned* g = grouped + (long long)b * CAPB;
    for (int i = tid; i < total; i += 256) g[i] = srt[i] & 0x1FFFFu;
}

// ---------------- pack per-edge norm: src -> (src<<15) | float15(dinv[src]) ----------------
__global__ __launch_bounds__(256) void qn2_k(const int* __restrict__ cur,
                                             const float* __restrict__ dinv,
                                             unsigned* __restrict__ grouped) {
    int b = blockIdx.x;
    int total = cur[b];
    if (total > CAPB) total = CAPB;
    unsigned* g = grouped + (long long)b * CAPB;
    for (int i = threadIdx.x; i < total; i += 256) {
        unsigned s = g[i];
        unsigned bits = __float_as_uint(dinv[s]);
        g[i] = (s << 15) | ((bits >> 12) & 0x7FFFu);
    }
}

// ---------------- CSR pull v7: feature-chunk sharded across XCDs ----------------
// chunk = bid & (NCH-1). With round-robin block->XCD dispatch, chunk c lives on XCD c
// (L1: 8 chunks x 3.2 MB slice; L2: 4 chunks x 3.2 MB slice, 2 XCDs each) -> slice is
// L2-resident, gathers become L2 hits, HBM table traffic drops ~NCH x.
// Block = 64 consecutive nodes (one bucket half) -> their grouped range is contiguous:
// stage it to LDS in one coalesced burst (<= CAPB words). 4 lanes per node (16 feats).
template <int NCH, bool BIAS, bool OUTB>
__global__ __launch_bounds__(256) void pull7_k(const unsigned* __restrict__ grouped,
                                               const int* __restrict__ rowstart,
                                               const int* __restrict__ cnt,
                                               const float* __restrict__ dinv,
                                               const ushort* __restrict__ tbl,
                                               const float* __restrict__ bias,
                                               void* __restrict__ outp) {
    __shared__ unsigned eds[CAPB];        // 12 KB
    int tid = threadIdx.x;
    int bid = blockIdx.x;
    int c  = bid & (NCH - 1);
    int nb = bid / NCH;
    int node0 = nb * 64;

    int nlast = node0 + 63; if (nlast >= NN) nlast = NN - 1;
    int base = rowstart[node0];
    int size = rowstart[nlast] + cnt[nlast] - base;
    for (int i = tid; i < size; i += 256)
        eds[i] = __builtin_nontemporal_load(&grouped[base + i]);

    int node = node0 + (tid >> 2);
    int lane = tid & 3;
    __syncthreads();
    if (node >= NN) return;

    const uint2* tc = (const uint2*)tbl + (long long)c * (NN * 4);
    float di = dinv[node];
    float w0 = di * di;
    float4 A = make_float4(0.f, 0.f, 0.f, 0.f);
    float4 B = make_float4(0.f, 0.f, 0.f, 0.f);
    {
        uint2 sv = tc[(unsigned)node * 4 + lane];
        acc4(A, sv, w0);                           // self-loop term
    }

    int deg = cnt[node];
    int off = rowstart[node] - base;

    int j = 0;
    if (deg >= 8) {
        uint2 v[8];
        float q[8];
#pragma unroll
        for (int t = 0; t < 8; t++) {
            unsigned e = eds[off + t];
            q[t] = decq(e) * di;
            v[t] = tc[(e >> 15) * 4 + lane];
        }
        for (; j + 16 <= deg; j += 8) {
#pragma unroll
            for (int t = 0; t < 8; t++) {
                unsigned e = eds[off + j + 8 + t];       // LDS, cheap
                uint2 nv = tc[(e >> 15) * 4 + lane];     // L2-resident gather
                if (t & 1) acc4(B, v[t], q[t]);
                else       acc4(A, v[t], q[t]);
                v[t] = nv; q[t] = decq(e) * di;
            }
        }
#pragma unroll
        for (int t = 0; t < 8; t++) {
            if (t & 1) acc4(B, v[t], q[t]);
            else       acc4(A, v[t], q[t]);
        }
        j += 8;
    }
    for (; j < deg; j++) {
        unsigned e = eds[off + j];
        uint2 v0 = tc[(e >> 15) * 4 + lane];
        acc4(A, v0, decq(e) * di);
    }

    float4 o;
    o.x = A.x + B.x; o.y = A.y + B.y; o.z = A.z + B.z; o.w = A.w + B.w;
    if (BIAS) {
        float4 bb = ((const float4*)bias)[c * 4 + lane];
        o.x += bb.x; o.y += bb.y; o.z += bb.z; o.w += bb.w;
    }
    if (OUTB) {
        // aggxb: standard [node][128] bf16 row layout (dgemm A-operand)
        uint2 p = packbf4(o);
        u32x2 pv; pv.x = p.x; pv.y = p.y;
        __builtin_nontemporal_store(pv,
            (u32x2*)&((uint2*)outp)[(long long)node * 32 + c * 4 + lane]);
    } else {
        // out: standard [node][64] fp32 row layout
        f32x4 ov; ov.x = o.x; ov.y = o.y; ov.z = o.z; ov.w = o.w;
        __builtin_nontemporal_store(ov,
            (f32x4*)&((float4*)outp)[(long long)node * 16 + c * 4 + lane]);
    }
}

// ---------------- MFMA fused double GEMM (H2 store in chunked layout) ----------------
__global__ __launch_bounds__(256) void dgemm_mfma_k(const ushort* __restrict__ Ab,
                                                    const ushort* __restrict__ W1t,
                                                    const float* __restrict__ b1,
                                                    const ushort* __restrict__ W2t,
                                                    ushort* __restrict__ H2b) {
    __shared__ ushort Tt[4][32 * DPAD];
    __shared__ ushort Ot[4][32 * OPAD];
    int tid = threadIdx.x;
    int wv = tid >> 6, lane = tid & 63;
    int m16 = lane & 15, quad = lane >> 4;
    int row0 = blockIdx.x * 128 + wv * 32;

    short8 af[2][4];
#pragma unroll
    for (int mt = 0; mt < 2; mt++)
#pragma unroll
        for (int kc = 0; kc < 4; kc++)
            af[mt][kc] = *(const short8*)(Ab + (long long)(row0 + mt * 16 + m16) * 128
                                          + kc * 32 + quad * 8);
    f32x4 accA[2][8];
#pragma unroll
    for (int mt = 0; mt < 2; mt++)
#pragma unroll
        for (int nt = 0; nt < 8; nt++) accA[mt][nt] = (f32x4){0.f, 0.f, 0.f, 0.f};

#pragma unroll
    for (int nt = 0; nt < 8; nt++) {
#pragma unroll
        for (int kc = 0; kc < 4; kc++) {
            short8 bf = *(const short8*)(W1t + (nt * 16 + m16) * 128 + kc * 32 + quad * 8);
            accA[0][nt] = __builtin_amdgcn_mfma_f32_16x16x32_bf16(af[0][kc], bf, accA[0][nt], 0, 0, 0);
            accA[1][nt] = __builtin_amdgcn_mfma_f32_16x16x32_bf16(af[1][kc], bf, accA[1][nt], 0, 0, 0);
        }
    }

#pragma unroll
    for (int nt = 0; nt < 8; nt++) {
        float bb = b1[nt * 16 + m16];
#pragma unroll
        for (int mt = 0; mt < 2; mt++)
#pragma unroll
            for (int r = 0; r < 4; r++) {
                float v = fmaxf(accA[mt][nt][r] + bb, 0.f);
                Tt[wv][(mt * 16 + quad * 4 + r) * DPAD + nt * 16 + m16] = bf16rn(v);
            }
    }
    __syncthreads();

    f32x4 accB[2][4];
#pragma unroll
    for (int mt = 0; mt < 2; mt++)
#pragma unroll
        for (int nt = 0; nt < 4; nt++) accB[mt][nt] = (f32x4){0.f, 0.f, 0.f, 0.f};

#pragma unroll
    for (int nt = 0; nt < 4; nt++) {
#pragma unroll
        for (int kc = 0; kc < 4; kc++) {
            short8 bf = *(const short8*)(W2t + (nt * 16 + m16) * 128 + kc * 32 + quad * 8);
#pragma unroll
            for (int mt = 0; mt < 2; mt++) {
                short8 aT = *(const short8*)(&Tt[wv][(mt * 16 + m16) * DPAD + kc * 32 + quad * 8]);
                accB[mt][nt] = __builtin_amdgcn_mfma_f32_16x16x32_bf16(aT, bf, accB[mt][nt], 0, 0, 0);
            }
        }
    }

#pragma unroll
    for (int nt = 0; nt < 4; nt++)
#pragma unroll
        for (int mt = 0; mt < 2; mt++)
#pragma unroll
            for (int r = 0; r < 4; r++)
                Ot[wv][(mt * 16 + quad * 4 + r) * OPAD + nt * 16 + m16] = bf16rn(accB[mt][nt][r]);
    __syncthreads();

    uint4* H4 = (uint4*)H2b;
#pragma unroll
    for (int it = 0; it < 4; it++) {
        int idx = it * 64 + lane;
        int r = idx >> 3, cc = idx & 7;        // cc: 8-feat group (feats [8cc, 8cc+8))
        int grow = row0 + r;
        if (grow < NN) {
            uint4 v = *(const uint4*)(&Ot[wv][r * OPAD + cc * 8]);
            // chunked layout: h2c[cc>>1][node][16 feats], uint4 pos = (cc&1)
            H4[(long long)(cc >> 1) * (NN * 2) + (long long)grow * 2 + (cc & 1)] = v;
        }
    }
}

// ---------------- launch ----------------
extern "C" void kernel_launch(void* const* d_in, const int* in_sizes, int n_in,
                              void* d_out, int out_size, void* d_ws, size_t ws_size,
                              hipStream_t stream) {
    const float* x  = (const float*)d_in[0];
    const void*  ei = d_in[1];
    const float* W1 = (const float*)d_in[2];
    const float* b1 = (const float*)d_in[3];
    const float* W2 = (const float*)d_in[4];
    const float* b2 = (const float*)d_in[5];
    float* out = (float*)d_out;
    char* ws = (char*)d_ws;

    // Layout (~89 MB of the >=125 MB proven ws):
    int*      flag     = (int*)ws;
    int*      cur      = (int*)(ws + 0x1000);        // 3.1 KB
    int*      cnt      = (int*)(ws + 0x10000);       // 400 KB
    int*      rowstart = (int*)(ws + 0x80000);       // 400 KB
    unsigned* bstage   = (unsigned*)(ws + 0x100000); // 9.6 MB
    unsigned* grouped  = (unsigned*)(ws + 0xB00000); // 9.6 MB (packed src|dinv15)
    ushort*   xc       = (ushort*)(ws + 0x1500000);  // 25.6 MB, 8-chunk layout
    ushort*   aggxb    = (ushort*)(ws + 0x2F00000);  // 25.6 MB, [node][128]
    ushort*   h2c      = (ushort*)(ws + 0x4800000);  // 12.8 MB, 4-chunk layout
    ushort*   W1t      = (ushort*)(ws + 0x5500000);  // 32 KB
    ushort*   W2t      = (ushort*)(ws + 0x5510000);  // 16 KB
    float*    dinv     = (float*)(ws + 0x5520000);   // 400 KB

    hipMemsetAsync(cur, 0, NB * sizeof(int), stream);
    detect_i64_k<<<1, 64, 0, stream>>>((const unsigned*)ei, flag);
    cast_xc_k<<<(NN * 32 + 255) / 256, 256, 0, stream>>>(x, xc);
    prep_wt_k<<<64, 256, 0, stream>>>(W1, W2, W1t, W2t);
    binfill_k<<<(NE + EPB - 1) / EPB, BFT, 0, stream>>>(ei, flag, cur, bstage);
    regroup_k<<<NB, 256, 0, stream>>>(cur, bstage, cnt, rowstart, grouped, dinv);
    qn2_k<<<NB, 256, 0, stream>>>(cur, dinv, grouped);

    // layer 1 aggregate: aggxb = bf16( A_norm @ x ), 8 feature-chunks sharded on XCDs
    pull7_k<8, false, true><<<8 * NPB, 256, 0, stream>>>(grouped, rowstart, cnt, dinv,
                                                         xc, nullptr, aggxb);
    // fused transforms on MFMA: h2c = bf16( relu(aggxb@W1 + b1) @ W2 ), chunked store
    dgemm_mfma_k<<<NROWPAD / 128, 256, 0, stream>>>(aggxb, W1t, b1, W2t, h2c);

    // layer 2 aggregate: out = A_norm @ h2 + b2 (fp32), 4 feature-chunks on XCD pairs
    pull7_k<4, true, false><<<4 * NPB, 256, 0, stream>>>(grouped, rowstart, cnt, dinv,
                                                         h2c, b2, out);
}

// Round 9
// 268.085 us; speedup vs baseline: 1.2715x; 1.2715x over previous
//
#include <hip/hip_runtime.h>

#define NN 100000
#define NE 1600000
#define NB 782            // buckets of 128 dst nodes
#define NBPAD 1024        // padded bucket count (1 per thread in 1024-thread binfill)
#define CAPB 3072         // staging/grouped capacity per bucket (mean 2046, 22 sigma)
#define EPB 8192          // edges per binning block (196 blocks, benign atomic count)
#define BFT 1024          // binfill threads (16 waves/CU -> latency cover)
#define NBF ((NE + EPB - 1) / EPB)            // 196 binfill blocks
#define NCAST2 ((NN * 32 + 1023) / 1024)      // 3125 cast blocks (1024 thr)
#define NPREP2 16                             // prep blocks (1024 thr)
#define NROWPAD 100096    // 782 * 128, dgemm row padding
#define DPAD 136          // T-tile row stride (ushort)
#define OPAD 72           // O-tile row stride (ushort)
#define MAXE 64           // LDS-staged edges per node (P(deg>64) ~ 0 at mean 16)

typedef __attribute__((ext_vector_type(8))) short short8;
typedef __attribute__((ext_vector_type(4))) float f32x4;

// ---------------- helpers ----------------
__device__ __forceinline__ unsigned short bf16rn(float f) {
    unsigned u = __float_as_uint(f);
    return (unsigned short)((u + 0x7FFFu + ((u >> 16) & 1u)) >> 16);
}
__device__ __forceinline__ float4 bf2x4(uint2 g) {
    float4 r;
    r.x = __uint_as_float(g.x << 16);
    r.y = __uint_as_float(g.x & 0xFFFF0000u);
    r.z = __uint_as_float(g.y << 16);
    r.w = __uint_as_float(g.y & 0xFFFF0000u);
    return r;
}
__device__ __forceinline__ uint2 packbf4(float4 v) {
    uint2 u;
    u.x = (unsigned)bf16rn(v.x) | ((unsigned)bf16rn(v.y) << 16);
    u.y = (unsigned)bf16rn(v.z) | ((unsigned)bf16rn(v.w) << 16);
    return u;
}
// accumulate 4 bf16 features (one uint2) scaled by q
__device__ __forceinline__ void acc4(float4& a, uint2 v, float q) {
    a.x = fmaf(__uint_as_float(v.x << 16), q, a.x);
    a.y = fmaf(__uint_as_float(v.x & 0xFFFF0000u), q, a.y);
    a.z = fmaf(__uint_as_float(v.y << 16), q, a.z);
    a.w = fmaf(__uint_as_float(v.y & 0xFFFF0000u), q, a.w);
}
// decode 15-bit packed dinv[src]: exp in [112,127], 11-bit mantissa
__device__ __forceinline__ float decq(unsigned e) {
    return __uint_as_float(0x38000000u | ((e & 0x7FFFu) << 12));
}
// bijective XCD-chunk swizzle (m204)
__device__ __forceinline__ int xcd_swz(int bid, int nwg) {
    int q = nwg >> 3, r = nwg & 7;
    int x = bid & 7, j = bid >> 3;
    int base = (x < r) ? x * (q + 1) : r * (q + 1) + (x - r) * q;
    return base + j;
}

__device__ __forceinline__ int load_node(const void* ei, int i64, long long idx) {
    return i64 ? (int)((const long long*)ei)[idx] : ((const int*)ei)[idx];
}

// ---------------- fused front: binfill [0,NBF) + cast + weight prep, 1024 threads ----------------
// binfill blocks dispatched first (critical path); cast/prep fill remaining CU slots.
// dtype detect inlined in wave 0 of each binfill block.
__global__ __launch_bounds__(1024) void front_k(const void* __restrict__ ei,
                                                int* __restrict__ cur,
                                                unsigned* __restrict__ bstage,
                                                const float* __restrict__ x,
                                                ushort* __restrict__ xb,
                                                const float* __restrict__ W1,
                                                const float* __restrict__ W2,
                                                ushort* __restrict__ W1t,
                                                ushort* __restrict__ W2t) {
    __shared__ unsigned binned[EPB];      // 32 KB
    __shared__ int lcnt[NBPAD];
    __shared__ int lpos[NBPAD];
    __shared__ int gbase[NBPAD];
    __shared__ int tsum[NBPAD];
    __shared__ int i64sh;
    int bid = blockIdx.x;
    int tid = threadIdx.x;

    if (bid >= NBF) {
        int cb = bid - NBF;
        if (cb < NCAST2) {
            // ---- cast role: fp32 -> bf16 feature stream (linear [node][128]) ----
            long long i = (long long)cb * 1024 + tid;
            if (i < (long long)NN * 32)
                ((uint2*)xb)[i] = packbf4(((const float4*)x)[i]);
        } else {
            // ---- weight prep role ----
            int i = (cb - NCAST2) * 1024 + tid;
            if (i < 128 * 128) {
                int k = i >> 7, n = i & 127;
                W1t[n * 128 + k] = bf16rn(W1[k * 128 + n]);
            }
            if (i < 128 * 64) {
                int k = i >> 6, n = i & 63;
                W2t[n * 128 + k] = bf16rn(W2[k * 64 + n]);
            }
        }
        return;
    }

    // ---- binfill role (proven round-6 config: EPB=8192, 16 waves/block) ----
    long long e0 = (long long)bid * EPB;

    // inline dtype detect (wave 0): i64 iff all high words of first 64 entries are 0
    if (tid < 64) {
        unsigned w = ((const unsigned*)ei)[2 * tid + 1];
        unsigned long long b = __ballot(w == 0u);
        if (tid == 0) i64sh = (b == 0xFFFFFFFFFFFFFFFFull) ? 1 : 0;
    }
    lcnt[tid] = 0;
    __syncthreads();
    int i64 = i64sh;

    // pass 1: histogram destination buckets (8 edges/thread)
    for (int i = tid; i < EPB; i += BFT) {
        long long e = e0 + i;
        if (e < NE) {
            int d = load_node(ei, i64, (long long)NE + e);
            atomicAdd(&lcnt[d >> 7], 1);
        }
    }
    __syncthreads();

    // Hillis-Steele inclusive scan, 1 counter per thread
    int c = lcnt[tid];
    tsum[tid] = c;
    __syncthreads();
    for (int off = 1; off < NBPAD; off <<= 1) {
        int v = (tid >= off) ? tsum[tid - off] : 0;
        __syncthreads();
        tsum[tid] += v;
        __syncthreads();
    }
    int excl = tsum[tid] - c;
    lcnt[tid] = excl;
    lpos[tid] = excl;
    if (tid < NB) gbase[tid] = c ? atomicAdd(&cur[tid], c) : 0;
    __syncthreads();

    // pass 2: re-read (L2-hot) and scatter into binned LDS
    for (int i = tid; i < EPB; i += BFT) {
        long long e = e0 + i;
        if (e < NE) {
            int sv = load_node(ei, i64, e);
            int d  = load_node(ei, i64, (long long)NE + e);
            int b  = d >> 7;
            int p  = atomicAdd(&lpos[b], 1);
            binned[p] = ((unsigned)(d & 127) << 17) | (unsigned)sv;
        }
    }
    __syncthreads();

    // flush: one bucket per thread, contiguous runs into bucket regions
    if (tid < NB) {
        int start = lcnt[tid], endp = lpos[tid];
        int gb = gbase[tid];
        unsigned* dst = bstage + (long long)tid * CAPB;
        for (int k = start; k < endp; k++) {
            int go = gb + (k - start);
            if (go < CAPB) dst[go] = binned[k];
        }
    }
}

// ---------------- per-bucket LDS regroup -> dense CSR (plain src ints) + deg ----------------
__global__ __launch_bounds__(256) void regroup_k(const int* __restrict__ cur,
                                                 const unsigned* __restrict__ bstage,
                                                 int* __restrict__ cnt,
                                                 int* __restrict__ rowstart,
                                                 unsigned* __restrict__ grouped,
                                                 float* __restrict__ dinv) {
    __shared__ unsigned stash[CAPB];
    __shared__ unsigned srt[CAPB];
    __shared__ int lcnt[128], lofs[128], lpos[128], sc[128];
    int tid = threadIdx.x;
    int b = blockIdx.x;

    int total = cur[b];
    if (total > CAPB) total = CAPB;
    const unsigned* seg = bstage + (long long)b * CAPB;
    for (int i = tid; i < total; i += 256) stash[i] = seg[i];
    __syncthreads();

    if (tid < 128) { lcnt[tid] = 0; lpos[tid] = 0; }
    __syncthreads();
    for (int i = tid; i < total; i += 256)
        atomicAdd(&lcnt[stash[i] >> 17], 1);
    __syncthreads();

    if (tid < 128) sc[tid] = lcnt[tid];
    __syncthreads();
    for (int off = 1; off < 128; off <<= 1) {
        int v = 0;
        if (tid < 128 && tid >= off) v = sc[tid - off];
        __syncthreads();
        if (tid < 128) sc[tid] += v;
        __syncthreads();
    }
    if (tid < 128) {
        lofs[tid] = sc[tid] - lcnt[tid];
        int node = b * 128 + tid;
        if (node < NN) {
            cnt[node] = lcnt[tid];
            rowstart[node] = b * CAPB + lofs[tid];
            dinv[node] = rsqrtf((float)(lcnt[tid] + 1));   // +1: self-loop
        }
    }
    __syncthreads();

    for (int i = tid; i < total; i += 256) {
        unsigned e = stash[i];
        int nl = e >> 17;
        int p = atomicAdd(&lpos[nl], 1);
        srt[lofs[nl] + p] = e;
    }
    __syncthreads();

    unsigned* g = grouped + (long long)b * CAPB;
    for (int i = tid; i < total; i += 256) g[i] = srt[i] & 0x1FFFFu;
}

// ---------------- pack per-edge norm: src -> (src<<15) | float15(dinv[src]) ----------------
__global__ __launch_bounds__(256) void qn2_k(const int* __restrict__ cur,
                                             const float* __restrict__ dinv,
                                             unsigned* __restrict__ grouped) {
    int b = blockIdx.x;
    int total = cur[b];
    if (total > CAPB) total = CAPB;
    unsigned* g = grouped + (long long)b * CAPB;
    for (int i = threadIdx.x; i < total; i += 256) {
        unsigned s = g[i];
        unsigned bits = __float_as_uint(dinv[s]);
        g[i] = (s << 15) | ((bits >> 12) & 0x7FFFu);
    }
}

// ---------------- CSR pull (round-6 champion): 4B packed edges in LDS + 8-deep pipeline ----------------
template <int LPN, bool BIAS, bool OUTB>
__global__ __launch_bounds__(256) void pull6_k(const unsigned* __restrict__ grouped,
                                               const int* __restrict__ rowstart,
                                               const int* __restrict__ cnt,
                                               const float* __restrict__ dinv,
                                               const ushort* __restrict__ hb,
                                               const float* __restrict__ bias,
                                               void* __restrict__ out) {
    __shared__ unsigned ed[256 / LPN][MAXE];  // LPN=32: 2 KB, LPN=16: 4 KB
    int tid = threadIdx.x;
    int nib = tid / LPN;
    int lane = tid & (LPN - 1);
    int node = xcd_swz(blockIdx.x, (int)gridDim.x) * (256 / LPN) + nib;
    if (node >= NN) return;

    const uint2* h2 = (const uint2*)hb;
    float di = dinv[node];
    float w0 = di * di;
    float4 A = make_float4(0.f, 0.f, 0.f, 0.f);
    float4 B = make_float4(0.f, 0.f, 0.f, 0.f);
    {
        float4 hv = bf2x4(h2[(unsigned)node * LPN + lane]);
        A.x = hv.x * w0; A.y = hv.y * w0; A.z = hv.z * w0; A.w = hv.w * w0;
    }

    int deg = cnt[node];
    const unsigned* row = grouped + rowstart[node];
    int s = deg < MAXE ? deg : MAXE;

    // stage this node's edges into LDS (contiguous 4B*LPN bursts, wave-internal)
    for (int t = lane; t < s; t += LPN) ed[nib][t] = row[t];

    int j = 0;
    if (s >= 8) {
        uint2 v[8];
        float q[8];
#pragma unroll
        for (int t = 0; t < 8; t++) {
            unsigned e = ed[nib][t];
            q[t] = decq(e) * di;
            v[t] = h2[(e >> 15) * LPN + lane];
        }
        for (; j + 16 <= s; j += 8) {
#pragma unroll
            for (int t = 0; t < 8; t++) {
                unsigned e = ed[nib][j + 8 + t];         // LDS, cheap
                uint2 nv = h2[(e >> 15) * LPN + lane];   // issue gather (next rotation)
                if (t & 1) acc4(B, v[t], q[t]);          // consume gather from 8 slots ago
                else       acc4(A, v[t], q[t]);
                v[t] = nv; q[t] = decq(e) * di;
            }
        }
#pragma unroll
        for (int t = 0; t < 8; t++) {
            if (t & 1) acc4(B, v[t], q[t]);
            else       acc4(A, v[t], q[t]);
        }
        j += 8;
    }
    for (; j < s; j++) {                                 // staged remainder (<8 left)
        unsigned e = ed[nib][j];
        uint2 v0 = h2[(e >> 15) * LPN + lane];
        acc4(A, v0, decq(e) * di);
    }
    for (; j < deg; j++) {                               // overflow beyond MAXE (rare)
        unsigned e = row[j];
        uint2 v0 = h2[(e >> 15) * LPN + lane];
        acc4(A, v0, decq(e) * di);
    }

    float4 o;
    o.x = A.x + B.x; o.y = A.y + B.y; o.z = A.z + B.z; o.w = A.w + B.w;
    if (BIAS) {
        float4 bb = ((const float4*)bias)[lane];
        o.x += bb.x; o.y += bb.y; o.z += bb.z; o.w += bb.w;
    }
    if (OUTB)
        ((uint2*)out)[(unsigned)node * LPN + lane] = packbf4(o);
    else
        ((float4*)out)[(unsigned)node * LPN + lane] = o;
}

// ---------------- MFMA fused double GEMM ----------------
__global__ __launch_bounds__(256) void dgemm_mfma_k(const ushort* __restrict__ Ab,
                                                    const ushort* __restrict__ W1t,
                                                    const float* __restrict__ b1,
                                                    const ushort* __restrict__ W2t,
                                                    ushort* __restrict__ H2b) {
    __shared__ ushort Tt[4][32 * DPAD];
    __shared__ ushort Ot[4][32 * OPAD];
    int tid = threadIdx.x;
    int wv = tid >> 6, lane = tid & 63;
    int m16 = lane & 15, quad = lane >> 4;
    int row0 = blockIdx.x * 128 + wv * 32;

    short8 af[2][4];
#pragma unroll
    for (int mt = 0; mt < 2; mt++)
#pragma unroll
        for (int kc = 0; kc < 4; kc++)
            af[mt][kc] = *(const short8*)(Ab + (long long)(row0 + mt * 16 + m16) * 128
                                          + kc * 32 + quad * 8);
    f32x4 accA[2][8];
#pragma unroll
    for (int mt = 0; mt < 2; mt++)
#pragma unroll
        for (int nt = 0; nt < 8; nt++) accA[mt][nt] = (f32x4){0.f, 0.f, 0.f, 0.f};

#pragma unroll
    for (int nt = 0; nt < 8; nt++) {
#pragma unroll
        for (int kc = 0; kc < 4; kc++) {
            short8 bf = *(const short8*)(W1t + (nt * 16 + m16) * 128 + kc * 32 + quad * 8);
            accA[0][nt] = __builtin_amdgcn_mfma_f32_16x16x32_bf16(af[0][kc], bf, accA[0][nt], 0, 0, 0);
            accA[1][nt] = __builtin_amdgcn_mfma_f32_16x16x32_bf16(af[1][kc], bf, accA[1][nt], 0, 0, 0);
        }
    }

#pragma unroll
    for (int nt = 0; nt < 8; nt++) {
        float bb = b1[nt * 16 + m16];
#pragma unroll
        for (int mt = 0; mt < 2; mt++)
#pragma unroll
            for (int r = 0; r < 4; r++) {
                float v = fmaxf(accA[mt][nt][r] + bb, 0.f);
                Tt[wv][(mt * 16 + quad * 4 + r) * DPAD + nt * 16 + m16] = bf16rn(v);
            }
    }
    __syncthreads();

    f32x4 accB[2][4];
#pragma unroll
    for (int mt = 0; mt < 2; mt++)
#pragma unroll
        for (int nt = 0; nt < 4; nt++) accB[mt][nt] = (f32x4){0.f, 0.f, 0.f, 0.f};

#pragma unroll
    for (int nt = 0; nt < 4; nt++) {
#pragma unroll
        for (int kc = 0; kc < 4; kc++) {
            short8 bf = *(const short8*)(W2t + (nt * 16 + m16) * 128 + kc * 32 + quad * 8);
#pragma unroll
            for (int mt = 0; mt < 2; mt++) {
                short8 aT = *(const short8*)(&Tt[wv][(mt * 16 + m16) * DPAD + kc * 32 + quad * 8]);
                accB[mt][nt] = __builtin_amdgcn_mfma_f32_16x16x32_bf16(aT, bf, accB[mt][nt], 0, 0, 0);
            }
        }
    }

#pragma unroll
    for (int nt = 0; nt < 4; nt++)
#pragma unroll
        for (int mt = 0; mt < 2; mt++)
#pragma unroll
            for (int r = 0; r < 4; r++)
                Ot[wv][(mt * 16 + quad * 4 + r) * OPAD + nt * 16 + m16] = bf16rn(accB[mt][nt][r]);
    __syncthreads();

    uint4* H4 = (uint4*)H2b;
#pragma unroll
    for (int it = 0; it < 4; it++) {
        int idx = it * 64 + lane;
        int r = idx >> 3, c = idx & 7;
        int grow = row0 + r;
        if (grow < NN) {
            uint4 v = *(const uint4*)(&Ot[wv][r * OPAD + c * 8]);
            H4[(long long)grow * 8 + c] = v;
        }
    }
}

// ---------------- launch ----------------
extern "C" void kernel_launch(void* const* d_in, const int* in_sizes, int n_in,
                              void* d_out, int out_size, void* d_ws, size_t ws_size,
                              hipStream_t stream) {
    const float* x  = (const float*)d_in[0];
    const void*  ei = d_in[1];
    const float* W1 = (const float*)d_in[2];
    const float* b1 = (const float*)d_in[3];
    const float* W2 = (const float*)d_in[4];
    const float* b2 = (const float*)d_in[5];
    float* out = (float*)d_out;
    char* ws = (char*)d_ws;

    // Layout (~89 MB of the >=125 MB proven ws):
    int*      cur      = (int*)(ws + 0x1000);        // 3.1 KB
    int*      cnt      = (int*)(ws + 0x10000);       // 400 KB
    int*      rowstart = (int*)(ws + 0x80000);       // 400 KB
    unsigned* bstage   = (unsigned*)(ws + 0x100000); // 9.6 MB
    unsigned* grouped  = (unsigned*)(ws + 0xB00000); // 9.6 MB (packed src|dinv15)
    ushort*   xb       = (ushort*)(ws + 0x1500000);  // 25.6 MB
    ushort*   aggxb    = (ushort*)(ws + 0x2F00000);  // 25.6 MB
    ushort*   h2b      = (ushort*)(ws + 0x4800000);  // 12.8 MB
    ushort*   W1t      = (ushort*)(ws + 0x5500000);  // 32 KB
    ushort*   W2t      = (ushort*)(ws + 0x5510000);  // 16 KB
    float*    dinv     = (float*)(ws + 0x5520000);   // 400 KB

    hipMemsetAsync(cur, 0, NB * sizeof(int), stream);

    // fused front: binfill (196 blocks, dispatched first) + cast (3125) + prep (16)
    front_k<<<NBF + NCAST2 + NPREP2, BFT, 0, stream>>>(ei, cur, bstage,
                                                       x, xb, W1, W2, W1t, W2t);

    regroup_k<<<NB, 256, 0, stream>>>(cur, bstage, cnt, rowstart, grouped, dinv);
    qn2_k<<<NB, 256, 0, stream>>>(cur, dinv, grouped);

    // layer 1 aggregate: aggxb = bf16( A_norm @ x ), LPN=32 (8 nodes/block)
    pull6_k<32, false, true><<<(NN + 7) / 8, 256, 0, stream>>>(grouped, rowstart, cnt, dinv,
                                                               xb, nullptr, aggxb);
    // fused transforms on MFMA: h2b = bf16( relu(aggxb@W1 + b1) @ W2 )
    dgemm_mfma_k<<<NROWPAD / 128, 256, 0, stream>>>(aggxb, W1t, b1, W2t, h2b);

    // layer 2 aggregate: out = A_norm @ h2 + b2 (fp32 out), LPN=16 (16 nodes/block)
    pull6_k<16, true, false><<<(NN + 15) / 16, 256, 0, stream>>>(grouped, rowstart, cnt, dinv,
                                                                 h2b, b2, out);
}